// Round 6
// baseline (2862.264 us; speedup 1.0000x reference)
//
#include <hip/hip_runtime.h>
#include <math.h>

#define BS 128
#define NW 80
#define NF 64
#define DD 768
#define INV_TAU 100.0f
#define SFW_LD 96
#define SWF_LD 72

typedef unsigned short u16;
typedef unsigned int u32;
typedef __attribute__((ext_vector_type(8))) short bf16x8;
typedef __attribute__((ext_vector_type(4))) float f32x4;

__device__ __forceinline__ u16 f2bf(float x) {
    unsigned b = __float_as_uint(x);
    return (u16)((b + 0x7fffu + ((b >> 16) & 1u)) >> 16);
}
__device__ __forceinline__ float bf2f(u16 h) { return __uint_as_float(((unsigned)h) << 16); }

__device__ __forceinline__ void gload_lds16(const void* gsrc, void* ldst) {
    __builtin_amdgcn_global_load_lds(
        (const __attribute__((address_space(1))) unsigned int*)gsrc,
        (__attribute__((address_space(3))) unsigned int*)ldst, 16, 0, 0);
}

// ---------------- K1: sg = sentence_output @ global_mat_weight ----------------
__global__ __launch_bounds__(256) void k_sent_global(
    const float* __restrict__ sent, const float* __restrict__ G, float* __restrict__ sg)
{
    int idx = blockIdx.x * 256 + threadIdx.x;
    int t = idx / DD, e = idx % DD;
    const float* srow = sent + t * DD;
    float acc = 0.f;
    #pragma unroll 4
    for (int d = 0; d < DD; ++d) acc += srow[d] * G[d * DD + e];
    sg[idx] = acc;
}

// ---------------- K1b: sim = 0.25 * sg @ traj^T ----------------
__global__ __launch_bounds__(256) void k_traj_sent(
    const float* __restrict__ sg, const float* __restrict__ traj, float* __restrict__ sim)
{
    __shared__ float ss[16][33], tt[16][33];
    int tx = threadIdx.x & 15, ty = threadIdx.x >> 4;
    int t0 = blockIdx.y * 16, v0 = blockIdx.x * 16;
    float acc = 0.f;
    for (int kk = 0; kk < DD; kk += 32) {
        for (int l = threadIdx.x; l < 16 * 32; l += 256) {
            int r = l >> 5, c = l & 31;
            ss[r][c] = sg[(t0 + r) * DD + kk + c];
            tt[r][c] = traj[(v0 + r) * DD + kk + c];
        }
        __syncthreads();
        #pragma unroll
        for (int k = 0; k < 32; ++k) acc += ss[ty][k] * tt[tx][k];
        __syncthreads();
    }
    sim[(t0 + ty) * BS + v0 + tx] = 0.25f * acc;
}

// ---------------- K_prepw: Wm_pad[80][96] hi/lo (row-major, u-pad 0), Fm[64][64] hi/lo ----------------
__global__ __launch_bounds__(256) void k_prepw(
    const float* __restrict__ Wm, const float* __restrict__ Fm,
    u16* __restrict__ Wm_hi, u16* __restrict__ Wm_lo,
    u16* __restrict__ Fm_hi, u16* __restrict__ Fm_lo)
{
    int gid = blockIdx.x * 256 + threadIdx.x;
    if (gid < 80 * 96) {
        int w = gid / 96, u = gid % 96;
        float x = (u < 80) ? Wm[w * 80 + u] : 0.f;
        u16 h = f2bf(x);
        Wm_hi[gid] = h; Wm_lo[gid] = f2bf(x - bf2f(h));
    } else if (gid < 80 * 96 + 64 * 64) {
        int j = gid - 80 * 96;
        float x = Fm[j];
        u16 h = f2bf(x);
        Fm_hi[j] = h; Fm_lo[j] = f2bf(x - bf2f(h));
    }
}

// ---------------- K2b: split ff to bf16 hi/lo ----------------
__global__ __launch_bounds__(256) void k_ffsplit(
    const float* __restrict__ x, u16* __restrict__ hi, u16* __restrict__ lo)
{
    int i = blockIdx.x * 256 + threadIdx.x;
    float4 f = *(const float4*)&x[(size_t)i * 4];
    ushort4 h, l;
    h.x = f2bf(f.x); l.x = f2bf(f.x - bf2f(h.x));
    h.y = f2bf(f.y); l.y = f2bf(f.y - bf2f(h.y));
    h.z = f2bf(f.z); l.z = f2bf(f.z - bf2f(h.z));
    h.w = f2bf(f.w); l.w = f2bf(f.w - bf2f(h.w));
    *(ushort4*)&hi[(size_t)i * 4] = h;
    *(ushort4*)&lo[(size_t)i * 4] = l;
}

// ---------------- K2: wl = wf @ L via split-bf16 MFMA ----------------
__global__ __launch_bounds__(256, 2) void k_wl(
    const float* __restrict__ wf, const float* __restrict__ L,
    u16* __restrict__ wl_hi, u16* __restrict__ wl_lo)
{
    __shared__ u16 Ah[128][72], Al[128][72];
    __shared__ u16 Bh[128][72], Bl[128][72];
    const int tid = threadIdx.x;
    const int lane = tid & 63, wid = tid >> 6;
    const int m0 = blockIdx.y * 128, n0 = blockIdx.x * 128;

    f32x4 acc[2][8];
    #pragma unroll
    for (int i = 0; i < 2; ++i)
        #pragma unroll
        for (int j = 0; j < 8; ++j) acc[i][j] = (f32x4){0.f, 0.f, 0.f, 0.f};

    for (int kk = 0; kk < DD; kk += 64) {
        #pragma unroll
        for (int p = 0; p < 8; ++p) {
            int row = p * 16 + (tid >> 4), c4 = tid & 15;
            float4 v = *(const float4*)&wf[(size_t)(m0 + row) * DD + kk + c4 * 4];
            ushort4 h, l;
            h.x = f2bf(v.x); l.x = f2bf(v.x - bf2f(h.x));
            h.y = f2bf(v.y); l.y = f2bf(v.y - bf2f(h.y));
            h.z = f2bf(v.z); l.z = f2bf(v.z - bf2f(h.z));
            h.w = f2bf(v.w); l.w = f2bf(v.w - bf2f(h.w));
            *(ushort4*)&Ah[row][c4 * 4] = h;
            *(ushort4*)&Al[row][c4 * 4] = l;
        }
        #pragma unroll
        for (int p = 0; p < 8; ++p) {
            int kr = p * 8 + (tid >> 5), c4 = tid & 31;
            float4 v = *(const float4*)&L[(size_t)(kk + kr) * DD + n0 + c4 * 4];
            #pragma unroll
            for (int jj = 0; jj < 4; ++jj) {
                int n = c4 * 4 + jj;
                float x = (jj == 0) ? v.x : (jj == 1) ? v.y : (jj == 2) ? v.z : v.w;
                u16 h = f2bf(x);
                int ka = kr ^ ((n & 7) << 3);
                Bh[n][ka] = h;
                Bl[n][ka] = f2bf(x - bf2f(h));
            }
        }
        __syncthreads();
        #pragma unroll
        for (int ks = 0; ks < 2; ++ks) {
            int koff = ks * 32 + (lane >> 4) * 8;
            bf16x8 ah[2], al[2];
            #pragma unroll
            for (int i = 0; i < 2; ++i) {
                int row = wid * 32 + 16 * i + (lane & 15);
                ah[i] = *(const bf16x8*)&Ah[row][koff];
                al[i] = *(const bf16x8*)&Al[row][koff];
            }
            #pragma unroll
            for (int j = 0; j < 8; ++j) {
                int n = 16 * j + (lane & 15);
                int kb = koff ^ ((n & 7) << 3);
                bf16x8 bh = *(const bf16x8*)&Bh[n][kb];
                bf16x8 bl = *(const bf16x8*)&Bl[n][kb];
                #pragma unroll
                for (int i = 0; i < 2; ++i) {
                    acc[i][j] = __builtin_amdgcn_mfma_f32_16x16x32_bf16(ah[i], bh, acc[i][j], 0, 0, 0);
                    acc[i][j] = __builtin_amdgcn_mfma_f32_16x16x32_bf16(ah[i], bl, acc[i][j], 0, 0, 0);
                    acc[i][j] = __builtin_amdgcn_mfma_f32_16x16x32_bf16(al[i], bh, acc[i][j], 0, 0, 0);
                }
            }
        }
        __syncthreads();
    }
    #pragma unroll
    for (int i = 0; i < 2; ++i)
        #pragma unroll
        for (int j = 0; j < 8; ++j)
            #pragma unroll
            for (int r = 0; r < 4; ++r) {
                float x = acc[i][j][r];
                int row = m0 + wid * 32 + 16 * i + ((lane >> 4) << 2) + r;
                int col = n0 + 16 * j + (lane & 15);
                size_t idx = (size_t)row * DD + col;
                u16 h = f2bf(x);
                wl_hi[idx] = h;
                wl_lo[idx] = f2bf(x - bf2f(h));
            }
}

// ---------------- K3: video_word (fp32, unchanged) ----------------
__global__ __launch_bounds__(256, 2) void k_video_word(
    const float* __restrict__ wf, const float* __restrict__ traj,
    const float* __restrict__ Wl, float* __restrict__ sim)
{
    __shared__ __align__(16) float As[NW][36];
    __shared__ __align__(16) float Bs[64][36];
    __shared__ float Am[NW][65];
    __shared__ float Pm[NW][65];
    int tx = threadIdx.x & 15, ty = threadIdx.x >> 4;
    int t = blockIdx.y, v0 = blockIdx.x * 64;
    const float* wft = wf + t * NW * DD;
    float acc[5][4] = {};
    for (int kk = 0; kk < DD; kk += 32) {
        for (int l = threadIdx.x; l < NW * 32; l += 256) {
            int w = l >> 5, k = l & 31;
            As[w][k] = wft[w * DD + kk + k];
        }
        for (int l = threadIdx.x; l < 64 * 32; l += 256) {
            int v = l >> 5, k = l & 31;
            Bs[v][k] = traj[(v0 + v) * DD + kk + k];
        }
        __syncthreads();
        #pragma unroll
        for (int k = 0; k < 32; k += 4) {
            float4 a[5], b[4];
            #pragma unroll
            for (int i = 0; i < 5; ++i) a[i] = *(const float4*)&As[tx + 16 * i][k];
            #pragma unroll
            for (int j = 0; j < 4; ++j) b[j] = *(const float4*)&Bs[ty + 16 * j][k];
            #pragma unroll
            for (int i = 0; i < 5; ++i)
                #pragma unroll
                for (int j = 0; j < 4; ++j)
                    acc[i][j] += a[i].x * b[j].x + a[i].y * b[j].y + a[i].z * b[j].z + a[i].w * b[j].w;
        }
        __syncthreads();
    }
    #pragma unroll
    for (int i = 0; i < 5; ++i)
        #pragma unroll
        for (int j = 0; j < 4; ++j) Am[tx + 16 * i][ty + 16 * j] = acc[i][j];
    __syncthreads();
    if (threadIdx.x < 64) {
        int v = threadIdx.x;
        float m = -1e30f;
        for (int w = 0; w < NW; ++w) m = fmaxf(m, Am[w][v]);
        float s = 0.f;
        for (int w = 0; w < NW; ++w) { float e = __expf((Am[w][v] - m) * INV_TAU); Pm[w][v] = e; s += e; }
        float r = 1.f / s;
        for (int w = 0; w < NW; ++w) Pm[w][v] *= r;
    }
    __syncthreads();
    float mm[5][4] = {};
    for (int w = 0; w < NW; ++w) {
        float a[5], b[4];
        #pragma unroll
        for (int i = 0; i < 5; ++i) a[i] = Wl[w * NW + tx + 16 * i];
        #pragma unroll
        for (int j = 0; j < 4; ++j) b[j] = Pm[w][ty + 16 * j];
        #pragma unroll
        for (int i = 0; i < 5; ++i)
            #pragma unroll
            for (int j = 0; j < 4; ++j) mm[i][j] += a[i] * b[j];
    }
    #pragma unroll
    for (int j = 0; j < 4; ++j) {
        float p = 0.f;
        #pragma unroll
        for (int i = 0; i < 5; ++i) p += mm[i][j] * Am[tx + 16 * i][ty + 16 * j];
        for (int o = 8; o; o >>= 1) p += __shfl_xor(p, o, 16);
        if (tx == 0) sim[t * BS + v0 + ty + 16 * j] += 0.25f * p;
    }
}

// ---------------- K4: sentence_frame (fp32, unchanged) ----------------
__global__ __launch_bounds__(256, 2) void k_sent_frame(
    const float* __restrict__ sent, const float* __restrict__ ff,
    const float* __restrict__ Fl, float* __restrict__ sim)
{
    __shared__ __align__(16) float Ss[64][36];
    __shared__ __align__(16) float Fs[64][36];
    __shared__ float Bm[64][65];
    __shared__ float Pm[64][65];
    int tx = threadIdx.x & 15, ty = threadIdx.x >> 4;
    int v = blockIdx.y, t0 = blockIdx.x * 64;
    const float* ffv = ff + v * NF * DD;
    float acc[4][4] = {};
    for (int kk = 0; kk < DD; kk += 32) {
        for (int l = threadIdx.x; l < 64 * 32; l += 256) {
            int r = l >> 5, k = l & 31;
            Ss[r][k] = sent[(t0 + r) * DD + kk + k];
            Fs[r][k] = ffv[r * DD + kk + k];
        }
        __syncthreads();
        #pragma unroll
        for (int k = 0; k < 32; k += 4) {
            float4 a[4], b[4];
            #pragma unroll
            for (int i = 0; i < 4; ++i) a[i] = *(const float4*)&Ss[tx + 16 * i][k];
            #pragma unroll
            for (int j = 0; j < 4; ++j) b[j] = *(const float4*)&Fs[ty + 16 * j][k];
            #pragma unroll
            for (int i = 0; i < 4; ++i)
                #pragma unroll
                for (int j = 0; j < 4; ++j)
                    acc[i][j] += a[i].x * b[j].x + a[i].y * b[j].y + a[i].z * b[j].z + a[i].w * b[j].w;
        }
        __syncthreads();
    }
    #pragma unroll
    for (int i = 0; i < 4; ++i)
        #pragma unroll
        for (int j = 0; j < 4; ++j) Bm[tx + 16 * i][ty + 16 * j] = acc[i][j];
    __syncthreads();
    if (threadIdx.x < 64) {
        int r = threadIdx.x;
        float m = -1e30f;
        for (int f = 0; f < NF; ++f) m = fmaxf(m, Bm[r][f]);
        float s = 0.f;
        for (int f = 0; f < NF; ++f) { float e = __expf((Bm[r][f] - m) * INV_TAU); Pm[r][f] = e; s += e; }
        float rr = 1.f / s;
        for (int f = 0; f < NF; ++f) Pm[r][f] *= rr;
    }
    __syncthreads();
    float nn[4][4] = {};
    for (int f = 0; f < NF; ++f) {
        float a[4], b[4];
        #pragma unroll
        for (int i = 0; i < 4; ++i) a[i] = Pm[ty + 16 * i][f];
        #pragma unroll
        for (int j = 0; j < 4; ++j) b[j] = Fl[f * NF + tx + 16 * j];
        #pragma unroll
        for (int i = 0; i < 4; ++i)
            #pragma unroll
            for (int j = 0; j < 4; ++j) nn[i][j] += a[i] * b[j];
    }
    #pragma unroll
    for (int i = 0; i < 4; ++i) {
        float p = 0.f;
        #pragma unroll
        for (int j = 0; j < 4; ++j) p += nn[i][j] * Bm[ty + 16 * i][tx + 16 * j];
        for (int o = 8; o; o >>= 1) p += __shfl_xor(p, o, 16);
        if (tx == 0) sim[(t0 + ty + 16 * i) * BS + v] += 0.25f * p;
    }
}

// ---------------- K5: frame_word — 2 v's per block, A-LDS dbuf + B-in-regs, cooperative post ----------------
// grid (64, 128): blockIdx.x = v-pair, blockIdx.y = t.
// wave wid: vi = wid>>1 (which v), half = wid&1 (f 32*half..+31). Each wave computes S[v][80][32].
__global__ __launch_bounds__(256, 3) void k_frame_word(
    const u16* __restrict__ wl_hi, const u16* __restrict__ wl_lo,
    const u16* __restrict__ ff_hi, const u16* __restrict__ ff_lo,
    const u16* __restrict__ Wm_hi, const u16* __restrict__ Wm_lo,
    const u16* __restrict__ Fm_hi, const u16* __restrict__ Fm_lo,
    const float* __restrict__ F2, const float* __restrict__ Wm2,
    float* __restrict__ sim)
{
    __shared__ __align__(16) union SH {
        u16 stage[2][10240];                          // 40960 B: [buf][A_hi 5120 u16 | A_lo 5120 u16]
        struct Post {
            union BigU {
                struct {                              // live rounds 0..1 (E/G phases)
                    u16 Sfw_h[64][SFW_LD], Sfw_l[64][SFW_LD];   // 24576 B (S^T: k=w contig)
                    u16 Swf_h[80][SWF_LD], Swf_l[80][SWF_LD];   // 23040 B (S: k=f contig)
                } S;
                struct {                              // live finals only (S dead)
                    float smw[2][64], smf[2][80];
                    float s2f[2], v2w[2];
                } F;
            } big;                                    // 47616 B
            float colM[64], colRD[64];                // 512
            float rowM[80], rowRD[80];                // 640
            float wlv[2][64];                         // 512
            float flv[2][80];                         // 640
            union RU {
                struct { float rowm_p[2][80], rows_p[2][80]; } a;
                struct { float part[4][80]; } b;
            } R;                                      // 1280
        } post;                                       // 51200 B total
    } sh;

    const int tid = threadIdx.x;
    const int lane = tid & 63, wid = tid >> 6;
    const int col = lane & 15, grp = lane >> 4;
    const int vi = wid >> 1, half = wid & 1;
    const int t = blockIdx.y, v0 = blockIdx.x * 2;
    const int v = v0 + vi;

    const int r8 = lane >> 3, s8 = lane & 7;
    const int gk = s8 ^ r8;                           // inverse-swizzled source k-group (rule 21)

    f32x4 acc[5][2];
    #pragma unroll
    for (int i = 0; i < 5; ++i) {
        acc[i][0] = (f32x4){0.f, 0.f, 0.f, 0.f};
        acc[i][1] = (f32x4){0.f, 0.f, 0.f, 0.f};
    }

    const size_t wlbase = (size_t)t * NW * DD;
    const size_t ffrow = ((size_t)v * NF + 32 * half + col) * DD;

    bf16x8 bh[2][2], bl[2][2];                        // [ks][j]

    auto loadB = [&](int kk) {
        #pragma unroll
        for (int ks = 0; ks < 2; ++ks)
            #pragma unroll
            for (int j = 0; j < 2; ++j) {
                size_t o = ffrow + (size_t)j * 16 * DD + kk + ks * 32 + grp * 8;
                bh[ks][j] = *(const bf16x8*)&ff_hi[o];
                bl[ks][j] = *(const bf16x8*)&ff_lo[o];
            }
    };
    auto stageA = [&](int buf, int kk) {
        for (int seg = wid; seg < 20; seg += 4) {
            int ishi = (seg < 10);
            int g = ishi ? seg : seg - 10;
            const u16* src = (ishi ? wl_hi : wl_lo) + wlbase + (size_t)(g * 8 + r8) * DD + kk + gk * 8;
            gload_lds16(src, (void*)&sh.stage[buf][(ishi ? 0 : 5120) + g * 512]);
        }
    };

    // ---- S-GEMM: S = wl_t[80x768] @ ff_v[64x768]^T, split-bf16 3-pass ----
    loadB(0);
    stageA(0, 0);
    __syncthreads();
    int cur = 0;
    for (int c = 0; c < 12; ++c) {
        const int kk = c * 64;
        if (c < 11) stageA(cur ^ 1, kk + 64);
        const u16* st = sh.stage[cur];
        #pragma unroll
        for (int ks = 0; ks < 2; ++ks) {
            const int sl = (ks << 2) + grp;
            bf16x8 afh[5], afl[5];
            #pragma unroll
            for (int i = 0; i < 5; ++i) {
                int row = col + 16 * i;
                int off = row * 64 + ((sl ^ (row & 7)) << 3);
                afh[i] = *(const bf16x8*)&st[off];
                afl[i] = *(const bf16x8*)&st[5120 + off];
            }
            #pragma unroll
            for (int i = 0; i < 5; ++i)
                #pragma unroll
                for (int j = 0; j < 2; ++j) {
                    acc[i][j] = __builtin_amdgcn_mfma_f32_16x16x32_bf16(afh[i], bh[ks][j], acc[i][j], 0, 0, 0);
                    acc[i][j] = __builtin_amdgcn_mfma_f32_16x16x32_bf16(afh[i], bl[ks][j], acc[i][j], 0, 0, 0);
                    acc[i][j] = __builtin_amdgcn_mfma_f32_16x16x32_bf16(afl[i], bh[ks][j], acc[i][j], 0, 0, 0);
                }
        }
        if (c < 11) loadB(kk + 64);
        __syncthreads();
        cur ^= 1;
    }
    // lane holds S[v][w=16i+4grp+r][f=32half+16j+col] in acc[i][j][r]

    auto& P = sh.post;
    const int myf = wid * 16 + col;

    for (int vr = 0; vr < 2; ++vr) {
        // --- PH_A: owner waves (vi==vr) write S packs + softmax stats ---
        if (vi == vr) {
            #pragma unroll
            for (int i = 0; i < 5; ++i)
                #pragma unroll
                for (int j = 0; j < 2; ++j) {
                    int f = 32 * half + 16 * j + col;
                    u16 hh[4], ll[4];
                    #pragma unroll
                    for (int r = 0; r < 4; ++r) {
                        float x = acc[i][j][r];
                        u16 h = f2bf(x); u16 l = f2bf(x - bf2f(h));
                        hh[r] = h; ll[r] = l;
                        int w = 16 * i + 4 * grp + r;
                        P.big.S.Swf_h[w][f] = h;
                        P.big.S.Swf_l[w][f] = l;
                    }
                    int wb = 16 * i + 4 * grp;
                    *(u32*)&P.big.S.Sfw_h[f][wb]     = (u32)hh[0] | ((u32)hh[1] << 16);
                    *(u32*)&P.big.S.Sfw_h[f][wb + 2] = (u32)hh[2] | ((u32)hh[3] << 16);
                    *(u32*)&P.big.S.Sfw_l[f][wb]     = (u32)ll[0] | ((u32)ll[1] << 16);
                    *(u32*)&P.big.S.Sfw_l[f][wb + 2] = (u32)ll[2] | ((u32)ll[3] << 16);
                }
            // column (over w) stats — fully in-wave per f
            #pragma unroll
            for (int j = 0; j < 2; ++j) {
                float m = -1e30f;
                #pragma unroll
                for (int i = 0; i < 5; ++i)
                    #pragma unroll
                    for (int r = 0; r < 4; ++r) m = fmaxf(m, acc[i][j][r]);
                m = fmaxf(m, __shfl_xor(m, 16));
                m = fmaxf(m, __shfl_xor(m, 32));
                float s = 0.f;
                #pragma unroll
                for (int i = 0; i < 5; ++i)
                    #pragma unroll
                    for (int r = 0; r < 4; ++r) s += __expf((acc[i][j][r] - m) * INV_TAU);
                s += __shfl_xor(s, 16);
                s += __shfl_xor(s, 32);
                if (grp == 0) {
                    int f = 32 * half + 16 * j + col;
                    P.colM[f] = m;
                    P.colRD[f] = 1.f / s;
                }
            }
            // row (over f) partial stats: (max, sum-given-max) per half, online-combinable
            #pragma unroll
            for (int i = 0; i < 5; ++i)
                #pragma unroll
                for (int r = 0; r < 4; ++r) {
                    float m = fmaxf(acc[i][0][r], acc[i][1][r]);
                    m = fmaxf(m, __shfl_xor(m, 1)); m = fmaxf(m, __shfl_xor(m, 2));
                    m = fmaxf(m, __shfl_xor(m, 4)); m = fmaxf(m, __shfl_xor(m, 8));
                    float s = __expf((acc[i][0][r] - m) * INV_TAU) + __expf((acc[i][1][r] - m) * INV_TAU);
                    s += __shfl_xor(s, 1); s += __shfl_xor(s, 2);
                    s += __shfl_xor(s, 4); s += __shfl_xor(s, 8);
                    if (col == 0) {
                        int w = 16 * i + 4 * grp + r;
                        P.R.a.rowm_p[half][w] = m;
                        P.R.a.rows_p[half][w] = s;
                    }
                }
        }
        __syncthreads();  // B1

        // --- PH_B: rowM/rowRD combine (tid<80) || E-GEMM: E = Wm @ S; wlv[f] = sum_w p1*E ---
        if (tid < 80) {
            float m0 = P.R.a.rowm_p[0][tid], m1 = P.R.a.rowm_p[1][tid];
            float s0 = P.R.a.rows_p[0][tid], s1 = P.R.a.rows_p[1][tid];
            float M = fmaxf(m0, m1);
            float Sd = s0 * __expf((m0 - M) * INV_TAU) + s1 * __expf((m1 - M) * INV_TAU);
            P.rowM[tid] = M;
            P.rowRD[tid] = 1.f / Sd;
        }
        float Sc[5][4];
        {
            f32x4 e1[5], e2[5];
            #pragma unroll
            for (int i = 0; i < 5; ++i) {
                e1[i] = (f32x4){0.f, 0.f, 0.f, 0.f};
                e2[i] = (f32x4){0.f, 0.f, 0.f, 0.f};
            }
            const u16* sfwh = &P.big.S.Sfw_h[0][0];
            const u16* sfwl = &P.big.S.Sfw_l[0][0];
            #pragma unroll
            for (int ks = 0; ks < 3; ++ks) {
                const int ko = ks * 32 + grp * 8;     // k up to 96; Wm rows are zero for k>=80
                bf16x8 sbh = *(const bf16x8*)&sfwh[myf * SFW_LD + ko];
                bf16x8 sbl = *(const bf16x8*)&sfwl[myf * SFW_LD + ko];
                #pragma unroll
                for (int i = 0; i < 5; ++i) {
                    int a = (col + 16 * i) * 96 + ko;
                    bf16x8 wh = *(const bf16x8*)&Wm_hi[a];
                    bf16x8 wl = *(const bf16x8*)&Wm_lo[a];
                    e1[i] = __builtin_amdgcn_mfma_f32_16x16x32_bf16(wh, sbh, e1[i], 0, 0, 0);
                    e2[i] = __builtin_amdgcn_mfma_f32_16x16x32_bf16(wh, sbl, e2[i], 0, 0, 0);
                    e1[i] = __builtin_amdgcn_mfma_f32_16x16x32_bf16(wl, sbh, e1[i], 0, 0, 0);
                }
            }
            float aw = 0.f;
            const float cM = P.colM[myf], cRD = P.colRD[myf];
            #pragma unroll
            for (int i = 0; i < 5; ++i)
                #pragma unroll
                for (int r = 0; r < 4; ++r) {
                    int w = 16 * i + 4 * grp + r;
                    float sx = bf2f(P.big.S.Swf_h[w][myf]) + bf2f(P.big.S.Swf_l[w][myf]);
                    Sc[i][r] = sx;
                    aw += __expf((sx - cM) * INV_TAU) * (e1[i][r] + e2[i][r]);
                }
            aw += __shfl_xor(aw, 16);
            aw += __shfl_xor(aw, 32);
            if (lane < 16) P.wlv[vr][myf] = aw * cRD;
        }
        __syncthreads();  // B2

        // --- PH_C: G-GEMM: G = S @ Fm^T; flv partials = sum_f p2*G ---
        {
            f32x4 g1[5], g2[5];
            #pragma unroll
            for (int i = 0; i < 5; ++i) {
                g1[i] = (f32x4){0.f, 0.f, 0.f, 0.f};
                g2[i] = (f32x4){0.f, 0.f, 0.f, 0.f};
            }
            const u16* swfh = &P.big.S.Swf_h[0][0];
            const u16* swfl = &P.big.S.Swf_l[0][0];
            #pragma unroll
            for (int ks = 0; ks < 2; ++ks) {
                const int ko = ks * 32 + grp * 8;
                bf16x8 fbh = *(const bf16x8*)&Fm_hi[myf * 64 + ko];
                bf16x8 fbl = *(const bf16x8*)&Fm_lo[myf * 64 + ko];
                #pragma unroll
                for (int i = 0; i < 5; ++i) {
                    int a = (col + 16 * i) * SWF_LD + ko;
                    bf16x8 ah = *(const bf16x8*)&swfh[a];
                    bf16x8 al = *(const bf16x8*)&swfl[a];
                    g1[i] = __builtin_amdgcn_mfma_f32_16x16x32_bf16(ah, fbh, g1[i], 0, 0, 0);
                    g2[i] = __builtin_amdgcn_mfma_f32_16x16x32_bf16(ah, fbl, g2[i], 0, 0, 0);
                    g1[i] = __builtin_amdgcn_mfma_f32_16x16x32_bf16(al, fbh, g1[i], 0, 0, 0);
                }
            }
            #pragma unroll
            for (int i = 0; i < 5; ++i)
                #pragma unroll
                for (int r = 0; r < 4; ++r) {
                    int w = 16 * i + 4 * grp + r;
                    float p2 = __expf((Sc[i][r] - P.rowM[w]) * INV_TAU) * P.rowRD[w];
                    float p = p2 * (g1[i][r] + g2[i][r]);
                    p += __shfl_xor(p, 1); p += __shfl_xor(p, 2);
                    p += __shfl_xor(p, 4); p += __shfl_xor(p, 8);
                    if (col == 0) P.R.b.part[wid][w] = p;
                }
        }
        __syncthreads();  // B3
        if (tid < 80)
            P.flv[vr][tid] = P.R.b.part[0][tid] + P.R.b.part[1][tid]
                           + P.R.b.part[2][tid] + P.R.b.part[3][tid];
        __syncthreads();  // B4
    }

    // --- FINALS (S buffers dead; big.F region) ---
    {
        const int fv = wid >> 1;
        if ((wid & 1) == 0) {                 // smw from wlv[fv]
            float x = P.wlv[fv][lane];
            float m = x;
            #pragma unroll
            for (int o = 32; o; o >>= 1) m = fmaxf(m, __shfl_xor(m, o));
            float e = __expf((x - m) * INV_TAU);
            float s = e;
            #pragma unroll
            for (int o = 32; o; o >>= 1) s += __shfl_xor(s, o);
            P.big.F.smw[fv][lane] = e / s;
        } else {                               // smf from flv[fv]
            float x0 = P.flv[fv][lane];
            float x1 = (lane < 16) ? P.flv[fv][64 + lane] : -1e30f;
            float m = fmaxf(x0, x1);
            #pragma unroll
            for (int o = 32; o; o >>= 1) m = fmaxf(m, __shfl_xor(m, o));
            float e0 = __expf((x0 - m) * INV_TAU);
            float e1 = (lane < 16) ? __expf((x1 - m) * INV_TAU) : 0.f;
            float s = e0 + e1;
            #pragma unroll
            for (int o = 32; o; o >>= 1) s += __shfl_xor(s, o);
            P.big.F.smf[fv][lane] = e0 / s;
            if (lane < 16) P.big.F.smf[fv][64 + lane] = e1 / s;
        }
    }
    __syncthreads();  // B5
    {
        const int fv = wid >> 1;
        if ((wid & 1) == 0) {                 // sent2frame
            float g = 0.f;
            for (int f = 0; f < NF; ++f) g += P.big.F.smw[fv][f] * F2[f * NF + lane];
            float p = g * P.wlv[fv][lane];
            #pragma unroll
            for (int o = 32; o; o >>= 1) p += __shfl_xor(p, o);
            if (lane == 0) P.big.F.s2f[fv] = p;
        } else {                               // video2word
            float g = 0.f;
            for (int w = 0; w < NW; ++w) g += P.big.F.smf[fv][w] * Wm2[w * NW + lane];
            float p = g * P.flv[fv][lane];
            if (lane < 16) {
                float g2 = 0.f;
                for (int w = 0; w < NW; ++w) g2 += P.big.F.smf[fv][w] * Wm2[w * NW + 64 + lane];
                p += g2 * P.flv[fv][64 + lane];
            }
            #pragma unroll
            for (int o = 32; o; o >>= 1) p += __shfl_xor(p, o);
            if (lane == 0) P.big.F.v2w[fv] = p;
        }
    }
    __syncthreads();  // B6
    if (tid < 2) sim[t * BS + v0 + tid] += 0.125f * (P.big.F.s2f[tid] + P.big.F.v2w[tid]);
}

// ---------------- K6: loss from sim ----------------
__global__ __launch_bounds__(256) void k_loss(const float* __restrict__ sim, float* __restrict__ out)
{
    __shared__ float S[BS][BS + 1];
    __shared__ float lr[BS], lc[BS];
    for (int l = threadIdx.x; l < BS * BS; l += 256) {
        int r = l >> 7, c = l & 127;
        S[r][c] = sim[l];
    }
    __syncthreads();
    int tid = threadIdx.x;
    if (tid < BS) {
        float m = -1e30f;
        for (int c = 0; c < BS; ++c) m = fmaxf(m, S[tid][c]);
        float s = 0.f;
        for (int c = 0; c < BS; ++c) s += __expf(S[tid][c] - m);
        lr[tid] = m + __logf(s);
    } else {
        int c = tid - BS;
        float m = -1e30f;
        for (int r = 0; r < BS; ++r) m = fmaxf(m, S[r][c]);
        float s = 0.f;
        for (int r = 0; r < BS; ++r) s += __expf(S[r][c] - m);
        lc[c] = m + __logf(s);
    }
    __syncthreads();
    if (tid == 0) {
        float a = 0.f;
        for (int i = 0; i < BS; ++i) a += S[i][i] - 0.5f * lr[i] - 0.5f * lc[i];
        out[0] = -a / (float)BS;
    }
}

extern "C" void kernel_launch(void* const* d_in, const int* in_sizes, int n_in,
                              void* d_out, int out_size, void* d_ws, size_t ws_size,
                              hipStream_t stream)
{
    const float* traj = (const float*)d_in[0];
    const float* ff   = (const float*)d_in[1];
    const float* sent = (const float*)d_in[2];
    const float* wf   = (const float*)d_in[3];
    const float* G    = (const float*)d_in[4];
    const float* Wl   = (const float*)d_in[5];
    const float* Fl   = (const float*)d_in[6];
    const float* L    = (const float*)d_in[7];
    const float* Fm   = (const float*)d_in[8];
    const float* Wm   = (const float*)d_in[9];
    const float* F2   = (const float*)d_in[10];
    const float* Wm2  = (const float*)d_in[11];
    float* out = (float*)d_out;
    char* base = (char*)d_ws;

    // ws layout (bytes)
    float* sg     = (float*)(base);                 // 393216
    float* sim    = (float*)(base + 393216);        // 65536
    u16*   wl_hi  = (u16*)(base + 458752);          // 15728640
    u16*   wl_lo  = (u16*)(base + 16187392);        // 15728640
    u16*   ff_hi  = (u16*)(base + 31916032);        // 12582912
    u16*   ff_lo  = (u16*)(base + 44498944);        // 12582912
    u16*   Wm_hi  = (u16*)(base + 57081856);        // 15360
    u16*   Wm_lo  = (u16*)(base + 57097216);        // 15360
    u16*   Fm_hi  = (u16*)(base + 57112576);        // 8192
    u16*   Fm_lo  = (u16*)(base + 57120768);        // 8192 -> 57128960 total

    hipLaunchKernelGGL(k_sent_global, dim3(BS * DD / 256), dim3(256), 0, stream, sent, G, sg);
    hipLaunchKernelGGL(k_traj_sent, dim3(8, 8), dim3(256), 0, stream, sg, traj, sim);
    hipLaunchKernelGGL(k_prepw, dim3(46), dim3(256), 0, stream, Wm, Fm, Wm_hi, Wm_lo, Fm_hi, Fm_lo);
    hipLaunchKernelGGL(k_ffsplit, dim3(BS * NF * DD / 1024), dim3(256), 0, stream, ff, ff_hi, ff_lo);
    hipLaunchKernelGGL(k_wl, dim3(6, 80), dim3(256), 0, stream, wf, L, wl_hi, wl_lo);
    hipLaunchKernelGGL(k_video_word, dim3(2, BS), dim3(256), 0, stream, wf, traj, Wl, sim);
    hipLaunchKernelGGL(k_sent_frame, dim3(2, BS), dim3(256), 0, stream, sent, ff, Fl, sim);
    hipLaunchKernelGGL(k_frame_word, dim3(BS / 2, BS), dim3(256), 0, stream,
                       wl_hi, wl_lo, ff_hi, ff_lo, Wm_hi, Wm_lo, Fm_hi, Fm_lo, F2, Wm2, sim);
    hipLaunchKernelGGL(k_loss, dim3(1), dim3(256), 0, stream, sim, out);
}

// Round 7
// 1853.799 us; speedup vs baseline: 1.5440x; 1.5440x over previous
//
#include <hip/hip_runtime.h>
#include <math.h>

#define BS 128
#define NW 80
#define NF 64
#define DD 768
#define INV_TAU 100.0f

typedef unsigned short u16;
typedef unsigned int u32;
typedef __attribute__((ext_vector_type(8))) short bf16x8;
typedef __attribute__((ext_vector_type(4))) float f32x4;

__device__ __forceinline__ u16 f2bf(float x) {
    unsigned b = __float_as_uint(x);
    return (u16)((b + 0x7fffu + ((b >> 16) & 1u)) >> 16);
}
__device__ __forceinline__ float bf2f(u16 h) { return __uint_as_float(((unsigned)h) << 16); }

__device__ __forceinline__ void gload_lds16(const void* gsrc, void* ldst) {
    __builtin_amdgcn_global_load_lds(
        (const __attribute__((address_space(1))) unsigned int*)gsrc,
        (__attribute__((address_space(3))) unsigned int*)ldst, 16, 0, 0);
}

// ---------------- K1: sg = sentence_output @ global_mat_weight ----------------
__global__ __launch_bounds__(256) void k_sent_global(
    const float* __restrict__ sent, const float* __restrict__ G, float* __restrict__ sg)
{
    int idx = blockIdx.x * 256 + threadIdx.x;
    int t = idx / DD, e = idx % DD;
    const float* srow = sent + t * DD;
    float acc = 0.f;
    #pragma unroll 4
    for (int d = 0; d < DD; ++d) acc += srow[d] * G[d * DD + e];
    sg[idx] = acc;
}

// ---------------- K1b: sim = 0.25 * sg @ traj^T ----------------
__global__ __launch_bounds__(256) void k_traj_sent(
    const float* __restrict__ sg, const float* __restrict__ traj, float* __restrict__ sim)
{
    __shared__ float ss[16][33], tt[16][33];
    int tx = threadIdx.x & 15, ty = threadIdx.x >> 4;
    int t0 = blockIdx.y * 16, v0 = blockIdx.x * 16;
    float acc = 0.f;
    for (int kk = 0; kk < DD; kk += 32) {
        for (int l = threadIdx.x; l < 16 * 32; l += 256) {
            int r = l >> 5, c = l & 31;
            ss[r][c] = sg[(t0 + r) * DD + kk + c];
            tt[r][c] = traj[(v0 + r) * DD + kk + c];
        }
        __syncthreads();
        #pragma unroll
        for (int k = 0; k < 32; ++k) acc += ss[ty][k] * tt[tx][k];
        __syncthreads();
    }
    sim[(t0 + ty) * BS + v0 + tx] = 0.25f * acc;
}

// ---------------- K_prepw: Wm_pad[80][96] hi/lo (row-major, k-pad 0), Fm[64][64] hi/lo ----------------
__global__ __launch_bounds__(256) void k_prepw(
    const float* __restrict__ Wm, const float* __restrict__ Fm,
    u16* __restrict__ Wm_hi, u16* __restrict__ Wm_lo,
    u16* __restrict__ Fm_hi, u16* __restrict__ Fm_lo)
{
    int gid = blockIdx.x * 256 + threadIdx.x;
    if (gid < 80 * 96) {
        int w = gid / 96, u = gid % 96;
        float x = (u < 80) ? Wm[w * 80 + u] : 0.f;
        u16 h = f2bf(x);
        Wm_hi[gid] = h; Wm_lo[gid] = f2bf(x - bf2f(h));
    } else if (gid < 80 * 96 + 64 * 64) {
        int j = gid - 80 * 96;
        float x = Fm[j];
        u16 h = f2bf(x);
        Fm_hi[j] = h; Fm_lo[j] = f2bf(x - bf2f(h));
    }
}

// ---------------- K2b: split ff to bf16 hi/lo ----------------
__global__ __launch_bounds__(256) void k_ffsplit(
    const float* __restrict__ x, u16* __restrict__ hi, u16* __restrict__ lo)
{
    int i = blockIdx.x * 256 + threadIdx.x;
    float4 f = *(const float4*)&x[(size_t)i * 4];
    ushort4 h, l;
    h.x = f2bf(f.x); l.x = f2bf(f.x - bf2f(h.x));
    h.y = f2bf(f.y); l.y = f2bf(f.y - bf2f(h.y));
    h.z = f2bf(f.z); l.z = f2bf(f.z - bf2f(h.z));
    h.w = f2bf(f.w); l.w = f2bf(f.w - bf2f(h.w));
    *(ushort4*)&hi[(size_t)i * 4] = h;
    *(ushort4*)&lo[(size_t)i * 4] = l;
}

// ---------------- K2: wl = wf @ L via split-bf16 MFMA ----------------
__global__ __launch_bounds__(256, 2) void k_wl(
    const float* __restrict__ wf, const float* __restrict__ L,
    u16* __restrict__ wl_hi, u16* __restrict__ wl_lo)
{
    __shared__ u16 Ah[128][72], Al[128][72];
    __shared__ u16 Bh[128][72], Bl[128][72];
    const int tid = threadIdx.x;
    const int lane = tid & 63, wid = tid >> 6;
    const int m0 = blockIdx.y * 128, n0 = blockIdx.x * 128;

    f32x4 acc[2][8];
    #pragma unroll
    for (int i = 0; i < 2; ++i)
        #pragma unroll
        for (int j = 0; j < 8; ++j) acc[i][j] = (f32x4){0.f, 0.f, 0.f, 0.f};

    for (int kk = 0; kk < DD; kk += 64) {
        #pragma unroll
        for (int p = 0; p < 8; ++p) {
            int row = p * 16 + (tid >> 4), c4 = tid & 15;
            float4 v = *(const float4*)&wf[(size_t)(m0 + row) * DD + kk + c4 * 4];
            ushort4 h, l;
            h.x = f2bf(v.x); l.x = f2bf(v.x - bf2f(h.x));
            h.y = f2bf(v.y); l.y = f2bf(v.y - bf2f(h.y));
            h.z = f2bf(v.z); l.z = f2bf(v.z - bf2f(h.z));
            h.w = f2bf(v.w); l.w = f2bf(v.w - bf2f(h.w));
            *(ushort4*)&Ah[row][c4 * 4] = h;
            *(ushort4*)&Al[row][c4 * 4] = l;
        }
        #pragma unroll
        for (int p = 0; p < 8; ++p) {
            int kr = p * 8 + (tid >> 5), c4 = tid & 31;
            float4 v = *(const float4*)&L[(size_t)(kk + kr) * DD + n0 + c4 * 4];
            #pragma unroll
            for (int jj = 0; jj < 4; ++jj) {
                int n = c4 * 4 + jj;
                float x = (jj == 0) ? v.x : (jj == 1) ? v.y : (jj == 2) ? v.z : v.w;
                u16 h = f2bf(x);
                int ka = kr ^ ((n & 7) << 3);
                Bh[n][ka] = h;
                Bl[n][ka] = f2bf(x - bf2f(h));
            }
        }
        __syncthreads();
        #pragma unroll
        for (int ks = 0; ks < 2; ++ks) {
            int koff = ks * 32 + (lane >> 4) * 8;
            bf16x8 ah[2], al[2];
            #pragma unroll
            for (int i = 0; i < 2; ++i) {
                int row = wid * 32 + 16 * i + (lane & 15);
                ah[i] = *(const bf16x8*)&Ah[row][koff];
                al[i] = *(const bf16x8*)&Al[row][koff];
            }
            #pragma unroll
            for (int j = 0; j < 8; ++j) {
                int n = 16 * j + (lane & 15);
                int kb = koff ^ ((n & 7) << 3);
                bf16x8 bh = *(const bf16x8*)&Bh[n][kb];
                bf16x8 bl = *(const bf16x8*)&Bl[n][kb];
                #pragma unroll
                for (int i = 0; i < 2; ++i) {
                    acc[i][j] = __builtin_amdgcn_mfma_f32_16x16x32_bf16(ah[i], bh, acc[i][j], 0, 0, 0);
                    acc[i][j] = __builtin_amdgcn_mfma_f32_16x16x32_bf16(ah[i], bl, acc[i][j], 0, 0, 0);
                    acc[i][j] = __builtin_amdgcn_mfma_f32_16x16x32_bf16(al[i], bh, acc[i][j], 0, 0, 0);
                }
            }
        }
        __syncthreads();
    }
    #pragma unroll
    for (int i = 0; i < 2; ++i)
        #pragma unroll
        for (int j = 0; j < 8; ++j)
            #pragma unroll
            for (int r = 0; r < 4; ++r) {
                float x = acc[i][j][r];
                int row = m0 + wid * 32 + 16 * i + ((lane >> 4) << 2) + r;
                int col = n0 + 16 * j + (lane & 15);
                size_t idx = (size_t)row * DD + col;
                u16 h = f2bf(x);
                wl_hi[idx] = h;
                wl_lo[idx] = f2bf(x - bf2f(h));
            }
}

// ---------------- K3: video_word (fp32, unchanged) ----------------
__global__ __launch_bounds__(256, 2) void k_video_word(
    const float* __restrict__ wf, const float* __restrict__ traj,
    const float* __restrict__ Wl, float* __restrict__ sim)
{
    __shared__ __align__(16) float As[NW][36];
    __shared__ __align__(16) float Bs[64][36];
    __shared__ float Am[NW][65];
    __shared__ float Pm[NW][65];
    int tx = threadIdx.x & 15, ty = threadIdx.x >> 4;
    int t = blockIdx.y, v0 = blockIdx.x * 64;
    const float* wft = wf + t * NW * DD;
    float acc[5][4] = {};
    for (int kk = 0; kk < DD; kk += 32) {
        for (int l = threadIdx.x; l < NW * 32; l += 256) {
            int w = l >> 5, k = l & 31;
            As[w][k] = wft[w * DD + kk + k];
        }
        for (int l = threadIdx.x; l < 64 * 32; l += 256) {
            int v = l >> 5, k = l & 31;
            Bs[v][k] = traj[(v0 + v) * DD + kk + k];
        }
        __syncthreads();
        #pragma unroll
        for (int k = 0; k < 32; k += 4) {
            float4 a[5], b[4];
            #pragma unroll
            for (int i = 0; i < 5; ++i) a[i] = *(const float4*)&As[tx + 16 * i][k];
            #pragma unroll
            for (int j = 0; j < 4; ++j) b[j] = *(const float4*)&Bs[ty + 16 * j][k];
            #pragma unroll
            for (int i = 0; i < 5; ++i)
                #pragma unroll
                for (int j = 0; j < 4; ++j)
                    acc[i][j] += a[i].x * b[j].x + a[i].y * b[j].y + a[i].z * b[j].z + a[i].w * b[j].w;
        }
        __syncthreads();
    }
    #pragma unroll
    for (int i = 0; i < 5; ++i)
        #pragma unroll
        for (int j = 0; j < 4; ++j) Am[tx + 16 * i][ty + 16 * j] = acc[i][j];
    __syncthreads();
    if (threadIdx.x < 64) {
        int v = threadIdx.x;
        float m = -1e30f;
        for (int w = 0; w < NW; ++w) m = fmaxf(m, Am[w][v]);
        float s = 0.f;
        for (int w = 0; w < NW; ++w) { float e = __expf((Am[w][v] - m) * INV_TAU); Pm[w][v] = e; s += e; }
        float r = 1.f / s;
        for (int w = 0; w < NW; ++w) Pm[w][v] *= r;
    }
    __syncthreads();
    float mm[5][4] = {};
    for (int w = 0; w < NW; ++w) {
        float a[5], b[4];
        #pragma unroll
        for (int i = 0; i < 5; ++i) a[i] = Wl[w * NW + tx + 16 * i];
        #pragma unroll
        for (int j = 0; j < 4; ++j) b[j] = Pm[w][ty + 16 * j];
        #pragma unroll
        for (int i = 0; i < 5; ++i)
            #pragma unroll
            for (int j = 0; j < 4; ++j) mm[i][j] += a[i] * b[j];
    }
    #pragma unroll
    for (int j = 0; j < 4; ++j) {
        float p = 0.f;
        #pragma unroll
        for (int i = 0; i < 5; ++i) p += mm[i][j] * Am[tx + 16 * i][ty + 16 * j];
        for (int o = 8; o; o >>= 1) p += __shfl_xor(p, o, 16);
        if (tx == 0) sim[t * BS + v0 + ty + 16 * j] += 0.25f * p;
    }
}

// ---------------- K4: sentence_frame (fp32, unchanged) ----------------
__global__ __launch_bounds__(256, 2) void k_sent_frame(
    const float* __restrict__ sent, const float* __restrict__ ff,
    const float* __restrict__ Fl, float* __restrict__ sim)
{
    __shared__ __align__(16) float Ss[64][36];
    __shared__ __align__(16) float Fs[64][36];
    __shared__ float Bm[64][65];
    __shared__ float Pm[64][65];
    int tx = threadIdx.x & 15, ty = threadIdx.x >> 4;
    int v = blockIdx.y, t0 = blockIdx.x * 64;
    const float* ffv = ff + v * NF * DD;
    float acc[4][4] = {};
    for (int kk = 0; kk < DD; kk += 32) {
        for (int l = threadIdx.x; l < 64 * 32; l += 256) {
            int r = l >> 5, k = l & 31;
            Ss[r][k] = sent[(t0 + r) * DD + kk + k];
            Fs[r][k] = ffv[r * DD + kk + k];
        }
        __syncthreads();
        #pragma unroll
        for (int k = 0; k < 32; k += 4) {
            float4 a[4], b[4];
            #pragma unroll
            for (int i = 0; i < 4; ++i) a[i] = *(const float4*)&Ss[tx + 16 * i][k];
            #pragma unroll
            for (int j = 0; j < 4; ++j) b[j] = *(const float4*)&Fs[ty + 16 * j][k];
            #pragma unroll
            for (int i = 0; i < 4; ++i)
                #pragma unroll
                for (int j = 0; j < 4; ++j)
                    acc[i][j] += a[i].x * b[j].x + a[i].y * b[j].y + a[i].z * b[j].z + a[i].w * b[j].w;
        }
        __syncthreads();
    }
    #pragma unroll
    for (int i = 0; i < 4; ++i)
        #pragma unroll
        for (int j = 0; j < 4; ++j) Bm[tx + 16 * i][ty + 16 * j] = acc[i][j];
    __syncthreads();
    if (threadIdx.x < 64) {
        int r = threadIdx.x;
        float m = -1e30f;
        for (int f = 0; f < NF; ++f) m = fmaxf(m, Bm[r][f]);
        float s = 0.f;
        for (int f = 0; f < NF; ++f) { float e = __expf((Bm[r][f] - m) * INV_TAU); Pm[r][f] = e; s += e; }
        float rr = 1.f / s;
        for (int f = 0; f < NF; ++f) Pm[r][f] *= rr;
    }
    __syncthreads();
    float nn[4][4] = {};
    for (int f = 0; f < NF; ++f) {
        float a[4], b[4];
        #pragma unroll
        for (int i = 0; i < 4; ++i) a[i] = Pm[ty + 16 * i][f];
        #pragma unroll
        for (int j = 0; j < 4; ++j) b[j] = Fl[f * NF + tx + 16 * j];
        #pragma unroll
        for (int i = 0; i < 4; ++i)
            #pragma unroll
            for (int j = 0; j < 4; ++j) nn[i][j] += a[i] * b[j];
    }
    #pragma unroll
    for (int i = 0; i < 4; ++i) {
        float p = 0.f;
        #pragma unroll
        for (int j = 0; j < 4; ++j) p += nn[i][j] * Bm[ty + 16 * i][tx + 16 * j];
        for (int o = 8; o; o >>= 1) p += __shfl_xor(p, o, 16);
        if (tx == 0) sim[(t0 + ty + 16 * i) * BS + v] += 0.25f * p;
    }
}

// ---------------- K5: frame_word — r4 S-GEMM + E/G-algebra post (register softmax) ----------------
// grid (128,128): (v,t). lane owns S[w=16i+4grp+r][f=16wid+col] after S-GEMM.
__global__ __launch_bounds__(256, 4) void k_frame_word(
    const u16* __restrict__ wl_hi, const u16* __restrict__ wl_lo,
    const u16* __restrict__ ff_hi, const u16* __restrict__ ff_lo,
    const u16* __restrict__ Wm_hi, const u16* __restrict__ Wm_lo,
    const u16* __restrict__ Fm_hi, const u16* __restrict__ Fm_lo,
    const float* __restrict__ F2, const float* __restrict__ Wm2,
    float* __restrict__ sim)
{
    __shared__ __align__(16) union SH {
        u16 stage[18432];                       // 36864 B (S-GEMM staging)
        struct Post {
            union SU {                          // time-multiplexed S packs
                struct { u16 Sfw_h[64][104], Sfw_l[64][104]; } e;  // S^T (k=w contig), pad 80..95 zeroed
                struct { u16 Swf_h[80][72],  Swf_l[80][72];  } g;  // S (k=f contig)
            } S;                                // 26624 B
            float partA[4][80], partB[4][80];   // 2560
            float rowM[80], rowRD[80];          // 640
            float wlv[64], flv[80];             // 576
            float smw[64], smf[80];             // 576
            float s2f, v2w;                     // 8   -> 30984 B total
        } post;
    } sh;

    const int tid = threadIdx.x;
    const int lane = tid & 63, wid = tid >> 6;
    const int col = lane & 15, grp = lane >> 4;
    const int v = blockIdx.x, t = blockIdx.y;
    const int myf = 16 * wid + col;

    f32x4 acc[5], acc2[5];
    #pragma unroll
    for (int i = 0; i < 5; ++i) { acc[i] = (f32x4){0.f,0.f,0.f,0.f}; acc2[i] = (f32x4){0.f,0.f,0.f,0.f}; }

    const int r8 = lane >> 3, s8 = lane & 7;
    const int gk = s8 ^ r8;

    // ---- S-GEMM: S = wl_t[80x768] @ ff_v[64x768]^T, split-bf16 3-pass (r4-identical) ----
    for (int kk = 0; kk < DD; kk += 64) {
        for (int seg = wid; seg < 36; seg += 4) {
            const u16* src;
            int ldsoff;
            if (seg < 10) {
                int g = seg, row = g * 8 + r8;
                src = wl_hi + (size_t)(t * NW + row) * DD + kk + gk * 8;
                ldsoff = g * 512;
            } else if (seg < 20) {
                int g = seg - 10, row = g * 8 + r8;
                src = wl_lo + (size_t)(t * NW + row) * DD + kk + gk * 8;
                ldsoff = 5120 + g * 512;
            } else if (seg < 28) {
                int g = seg - 20, row = g * 8 + r8;
                src = ff_hi + (size_t)(v * NF + row) * DD + kk + gk * 8;
                ldsoff = 10240 + g * 512;
            } else {
                int g = seg - 28, row = g * 8 + r8;
                src = ff_lo + (size_t)(v * NF + row) * DD + kk + gk * 8;
                ldsoff = 14336 + g * 512;
            }
            gload_lds16(src, (void*)&sh.stage[ldsoff]);
        }
        __syncthreads();
        const u16* st = sh.stage;
        #pragma unroll
        for (int ks = 0; ks < 2; ++ks) {
            const int sl = (ks << 2) + grp;
            bf16x8 afh[5], afl[5], bfh, bfl;
            #pragma unroll
            for (int i = 0; i < 5; ++i) {
                int row = col + 16 * i;
                int off = row * 64 + ((sl ^ (row & 7)) << 3);
                afh[i] = *(const bf16x8*)&st[off];
                afl[i] = *(const bf16x8*)&st[5120 + off];
            }
            {
                int row = col + 16 * wid;
                int off = row * 64 + ((sl ^ (row & 7)) << 3);
                bfh = *(const bf16x8*)&st[10240 + off];
                bfl = *(const bf16x8*)&st[14336 + off];
            }
            #pragma unroll
            for (int i = 0; i < 5; ++i)
                acc[i] = __builtin_amdgcn_mfma_f32_16x16x32_bf16(afh[i], bfh, acc[i], 0, 0, 0);
            #pragma unroll
            for (int i = 0; i < 5; ++i)
                acc2[i] = __builtin_amdgcn_mfma_f32_16x16x32_bf16(afh[i], bfl, acc2[i], 0, 0, 0);
            #pragma unroll
            for (int i = 0; i < 5; ++i)
                acc[i] = __builtin_amdgcn_mfma_f32_16x16x32_bf16(afl[i], bfh, acc[i], 0, 0, 0);
        }
        __syncthreads();
    }

    auto& P = sh.post;

    // register S + hi/lo split (kept for both packs)
    float sv[5][4];
    u16 svh[5][4], svl[5][4];
    #pragma unroll
    for (int i = 0; i < 5; ++i)
        #pragma unroll
        for (int r = 0; r < 4; ++r) {
            float x = acc[i][r] + acc2[i][r];
            sv[i][r] = x;
            u16 h = f2bf(x);
            svh[i][r] = h;
            svl[i][r] = f2bf(x - bf2f(h));
        }

    // ---- Phase0: Sfw pack (+zero k-pad) + row-max partials; col stats in-reg ----
    {
        int fz = tid >> 2, qz = tid & 3;
        ushort4 z = {0, 0, 0, 0};
        *(ushort4*)&P.S.e.Sfw_h[fz][80 + 4 * qz] = z;
        *(ushort4*)&P.S.e.Sfw_l[fz][80 + 4 * qz] = z;
    }
    #pragma unroll
    for (int i = 0; i < 5; ++i) {
        int wb = 16 * i + 4 * grp;
        *(u32*)&P.S.e.Sfw_h[myf][wb]     = (u32)svh[i][0] | ((u32)svh[i][1] << 16);
        *(u32*)&P.S.e.Sfw_h[myf][wb + 2] = (u32)svh[i][2] | ((u32)svh[i][3] << 16);
        *(u32*)&P.S.e.Sfw_l[myf][wb]     = (u32)svl[i][0] | ((u32)svl[i][1] << 16);
        *(u32*)&P.S.e.Sfw_l[myf][wb + 2] = (u32)svl[i][2] | ((u32)svl[i][3] << 16);
    }
    #pragma unroll
    for (int i = 0; i < 5; ++i)
        #pragma unroll
        for (int r = 0; r < 4; ++r) {
            float m = sv[i][r];
            m = fmaxf(m, __shfl_xor(m, 1)); m = fmaxf(m, __shfl_xor(m, 2));
            m = fmaxf(m, __shfl_xor(m, 4)); m = fmaxf(m, __shfl_xor(m, 8));
            if (col == 0) P.partA[wid][16 * i + 4 * grp + r] = m;
        }
    float cm = -1e30f;
    #pragma unroll
    for (int i = 0; i < 5; ++i)
        #pragma unroll
        for (int r = 0; r < 4; ++r) cm = fmaxf(cm, sv[i][r]);
    cm = fmaxf(cm, __shfl_xor(cm, 16));
    cm = fmaxf(cm, __shfl_xor(cm, 32));
    float cs = 0.f;
    #pragma unroll
    for (int i = 0; i < 5; ++i)
        #pragma unroll
        for (int r = 0; r < 4; ++r) cs += __expf((sv[i][r] - cm) * INV_TAU);
    cs += __shfl_xor(cs, 16);
    cs += __shfl_xor(cs, 32);
    const float cRD = 1.f / cs;
    __syncthreads();  // B1

    // ---- Phase1: rowM finalize || E-GEMM (E = Wm @ S) + wlv ----
    if (tid < 80) {
        float m = P.partA[0][tid];
        m = fmaxf(m, P.partA[1][tid]);
        m = fmaxf(m, P.partA[2][tid]);
        m = fmaxf(m, P.partA[3][tid]);
        P.rowM[tid] = m;
    }
    {
        f32x4 e1[5], e2[5];
        #pragma unroll
        for (int i = 0; i < 5; ++i) { e1[i] = (f32x4){0.f,0.f,0.f,0.f}; e2[i] = (f32x4){0.f,0.f,0.f,0.f}; }
        #pragma unroll
        for (int ks = 0; ks < 3; ++ks) {
            const int ko = ks * 32 + grp * 8;
            bf16x8 sbh = *(const bf16x8*)&P.S.e.Sfw_h[myf][ko];
            bf16x8 sbl = *(const bf16x8*)&P.S.e.Sfw_l[myf][ko];
            #pragma unroll
            for (int i = 0; i < 5; ++i) {
                int a = (col + 16 * i) * 96 + ko;
                bf16x8 wh = *(const bf16x8*)&Wm_hi[a];
                bf16x8 wl = *(const bf16x8*)&Wm_lo[a];
                e1[i] = __builtin_amdgcn_mfma_f32_16x16x32_bf16(wh, sbh, e1[i], 0, 0, 0);
                e2[i] = __builtin_amdgcn_mfma_f32_16x16x32_bf16(wh, sbl, e2[i], 0, 0, 0);
                e1[i] = __builtin_amdgcn_mfma_f32_16x16x32_bf16(wl, sbh, e1[i], 0, 0, 0);
            }
        }
        float p = 0.f;
        #pragma unroll
        for (int i = 0; i < 5; ++i)
            #pragma unroll
            for (int r = 0; r < 4; ++r)
                p += __expf((sv[i][r] - cm) * INV_TAU) * (e1[i][r] + e2[i][r]);
        p += __shfl_xor(p, 16);
        p += __shfl_xor(p, 32);
        if (lane < 16) P.wlv[myf] = p * cRD;
    }
    __syncthreads();  // B2

    // ---- Phase2: Swf pack (overwrites Sfw) + p2 raw weights + row-sum partials ----
    #pragma unroll
    for (int i = 0; i < 5; ++i)
        #pragma unroll
        for (int r = 0; r < 4; ++r) {
            int w = 16 * i + 4 * grp + r;
            P.S.g.Swf_h[w][myf] = svh[i][r];
            P.S.g.Swf_l[w][myf] = svl[i][r];
        }
    float p2r[5][4];
    #pragma unroll
    for (int i = 0; i < 5; ++i)
        #pragma unroll
        for (int r = 0; r < 4; ++r) {
            int w = 16 * i + 4 * grp + r;
            p2r[i][r] = __expf((sv[i][r] - P.rowM[w]) * INV_TAU);
            float s = p2r[i][r];
            s += __shfl_xor(s, 1); s += __shfl_xor(s, 2);
            s += __shfl_xor(s, 4); s += __shfl_xor(s, 8);
            if (col == 0) P.partB[wid][w] = s;
        }
    __syncthreads();  // B3

    // ---- Phase3: rowRD finalize || G-GEMM (G = S @ Fm^T) + flv partials ----
    if (tid < 80)
        P.rowRD[tid] = 1.f / (P.partB[0][tid] + P.partB[1][tid] + P.partB[2][tid] + P.partB[3][tid]);
    {
        f32x4 g1[5], g2[5];
        #pragma unroll
        for (int i = 0; i < 5; ++i) { g1[i] = (f32x4){0.f,0.f,0.f,0.f}; g2[i] = (f32x4){0.f,0.f,0.f,0.f}; }
        #pragma unroll
        for (int ks = 0; ks < 2; ++ks) {
            const int ko = ks * 32 + grp * 8;
            bf16x8 fbh = *(const bf16x8*)&Fm_hi[myf * 64 + ko];
            bf16x8 fbl = *(const bf16x8*)&Fm_lo[myf * 64 + ko];
            #pragma unroll
            for (int i = 0; i < 5; ++i) {
                int a = (col + 16 * i) * 72 + ko;
                bf16x8 ah = *(const bf16x8*)&P.S.g.Swf_h[0][a];
                bf16x8 al = *(const bf16x8*)&P.S.g.Swf_l[0][a];
                g1[i] = __builtin_amdgcn_mfma_f32_16x16x32_bf16(ah, fbh, g1[i], 0, 0, 0);
                g2[i] = __builtin_amdgcn_mfma_f32_16x16x32_bf16(ah, fbl, g2[i], 0, 0, 0);
                g1[i] = __builtin_amdgcn_mfma_f32_16x16x32_bf16(al, fbh, g1[i], 0, 0, 0);
            }
        }
        #pragma unroll
        for (int i = 0; i < 5; ++i)
            #pragma unroll
            for (int r = 0; r < 4; ++r) {
                int w = 16 * i + 4 * grp + r;
                float p = p2r[i][r] * (g1[i][r] + g2[i][r]);
                p += __shfl_xor(p, 1); p += __shfl_xor(p, 2);
                p += __shfl_xor(p, 4); p += __shfl_xor(p, 8);
                if (col == 0) P.partA[wid][w] = p;
            }
    }
    __syncthreads();  // B4

    if (tid < 80)
        P.flv[tid] = P.rowRD[tid] * (P.partA[0][tid] + P.partA[1][tid] + P.partA[2][tid] + P.partA[3][tid]);
    __syncthreads();  // B5

    // ---- finals (wave-parallel) ----
    if (wid == 0) {
        float x = P.wlv[lane];
        float m = x;
        #pragma unroll
        for (int o = 32; o; o >>= 1) m = fmaxf(m, __shfl_xor(m, o));
        float e = __expf((x - m) * INV_TAU);
        float s = e;
        #pragma unroll
        for (int o = 32; o; o >>= 1) s += __shfl_xor(s, o);
        P.smw[lane] = e / s;
    } else if (wid == 1) {
        float x0 = P.flv[lane];
        float x1 = (lane < 16) ? P.flv[64 + lane] : -1e30f;
        float m = fmaxf(x0, x1);
        #pragma unroll
        for (int o = 32; o; o >>= 1) m = fmaxf(m, __shfl_xor(m, o));
        float e0 = __expf((x0 - m) * INV_TAU);
        float e1 = (lane < 16) ? __expf((x1 - m) * INV_TAU) : 0.f;
        float s = e0 + e1;
        #pragma unroll
        for (int o = 32; o; o >>= 1) s += __shfl_xor(s, o);
        P.smf[lane] = e0 / s;
        if (lane < 16) P.smf[64 + lane] = e1 / s;
    }
    __syncthreads();  // B6

    if (wid == 0) {                 // sent2frame
        float g = 0.f;
        for (int f = 0; f < NF; ++f) g += P.smw[f] * F2[f * NF + lane];
        float p = g * P.wlv[lane];
        #pragma unroll
        for (int o = 32; o; o >>= 1) p += __shfl_xor(p, o);
        if (lane == 0) P.s2f = p;
    } else if (wid == 1) {          // video2word
        float g = 0.f;
        for (int w = 0; w < NW; ++w) g += P.smf[w] * Wm2[w * NW + lane];
        float p = g * P.flv[lane];
        if (lane < 16) {
            float g2 = 0.f;
            for (int w = 0; w < NW; ++w) g2 += P.smf[w] * Wm2[w * NW + 64 + lane];
            p += g2 * P.flv[64 + lane];
        }
        #pragma unroll
        for (int o = 32; o; o >>= 1) p += __shfl_xor(p, o);
        if (lane == 0) P.v2w = p;
    }
    __syncthreads();  // B7
    if (tid == 0) sim[t * BS + v] += 0.125f * (P.s2f + P.v2w);
}

// ---------------- K6: loss from sim ----------------
__global__ __launch_bounds__(256) void k_loss(const float* __restrict__ sim, float* __restrict__ out)
{
    __shared__ float S[BS][BS + 1];
    __shared__ float lr[BS], lc[BS];
    for (int l = threadIdx.x; l < BS * BS; l += 256) {
        int r = l >> 7, c = l & 127;
        S[r][c] = sim[l];
    }
    __syncthreads();
    int tid = threadIdx.x;
    if (tid < BS) {
        float m = -1e30f;
        for (int c = 0; c < BS; ++c) m = fmaxf(m, S[tid][c]);
        float s = 0.f;
        for (int c = 0; c < BS; ++c) s += __expf(S[tid][c] - m);
        lr[tid] = m + __logf(s);
    } else {
        int c = tid - BS;
        float m = -1e30f;
        for (int r = 0; r < BS; ++r) m = fmaxf(m, S[r][c]);
        float s = 0.f;
        for (int r = 0; r < BS; ++r) s += __expf(S[r][c] - m);
        lc[c] = m + __logf(s);
    }
    __syncthreads();
    if (tid == 0) {
        float a = 0.f;
        for (int i = 0; i < BS; ++i) a += S[i][i] - 0.5f * lr[i] - 0.5f * lc[i];
        out[0] = -a / (float)BS;
    }
}

extern "C" void kernel_launch(void* const* d_in, const int* in_sizes, int n_in,
                              void* d_out, int out_size, void* d_ws, size_t ws_size,
                              hipStream_t stream)
{
    const float* traj = (const float*)d_in[0];
    const float* ff   = (const float*)d_in[1];
    const float* sent = (const float*)d_in[2];
    const float* wf   = (const float*)d_in[3];
    const float* G    = (const float*)d_in[4];
    const float* Wl   = (const float*)d_in[5];
    const float* Fl   = (const float*)d_in[6];
    const float* L    = (const float*)d_in[7];
    const float* Fm   = (const float*)d_in[8];
    const float* Wm   = (const float*)d_in[9];
    const float* F2   = (const float*)d_in[10];
    const float* Wm2  = (const float*)d_in[11];
    float* out = (float*)d_out;
    char* base = (char*)d_ws;

    // ws layout (bytes)
    float* sg     = (float*)(base);                 // 393216
    float* sim    = (float*)(base + 393216);        // 65536
    u16*   wl_hi  = (u16*)(base + 458752);          // 15728640
    u16*   wl_lo  = (u16*)(base + 16187392);        // 15728640
    u16*   ff_hi  = (u16*)(base + 31916032);        // 12582912
    u16*   ff_lo  = (u16*)(base + 44498944);        // 12582912
    u16*   Wm_hi  = (u16*)(base + 57081856);        // 15360
    u16*   Wm_lo  = (u16*)(base + 57097216);        // 15360
    u16*   Fm_hi  = (u16*)(base + 57112576);        // 8192
    u16*   Fm_lo  = (u16*)(base + 57120768);        // 8192 -> 57128960 total

    hipLaunchKernelGGL(k_sent_global, dim3(BS * DD / 256), dim3(256), 0, stream, sent, G, sg);
    hipLaunchKernelGGL(k_traj_sent, dim3(8, 8), dim3(256), 0, stream, sg, traj, sim);
    hipLaunchKernelGGL(k_prepw, dim3(46), dim3(256), 0, stream, Wm, Fm, Wm_hi, Wm_lo, Fm_hi, Fm_lo);
    hipLaunchKernelGGL(k_ffsplit, dim3(BS * NF * DD / 1024), dim3(256), 0, stream, ff, ff_hi, ff_lo);
    hipLaunchKernelGGL(k_wl, dim3(6, 80), dim3(256), 0, stream, wf, L, wl_hi, wl_lo);
    hipLaunchKernelGGL(k_video_word, dim3(2, BS), dim3(256), 0, stream, wf, traj, Wl, sim);
    hipLaunchKernelGGL(k_sent_frame, dim3(2, BS), dim3(256), 0, stream, sent, ff, Fl, sim);
    hipLaunchKernelGGL(k_frame_word, dim3(BS, BS), dim3(256), 0, stream,
                       wl_hi, wl_lo, ff_hi, ff_lo, Wm_hi, Wm_lo, Fm_hi, Fm_lo, F2, Wm2, sim);
    hipLaunchKernelGGL(k_loss, dim3(1), dim3(256), 0, stream, sim, out);
}